// Round 3
// baseline (975.245 us; speedup 1.0000x reference)
//
#include <hip/hip_runtime.h>
#include <cmath>

// Problem: B=16, S=512, H=1024, NH=16, DH=64.
// out = [ctx 16x512x1024][scores 16x16x512x512], fp32.
// Strategy: split-fp32 (hi/lo bf16, 3-term MFMA) for all GEMM-shaped work.
//   x = hi(trunc) + lo(rne residual); A*B ~= Ah*Bh + Ah*Bl + Al*Bh (err ~2^-17).
// Masked scores written as -1e30 (finite; exp(-1e30 - m) == 0 so softmax ok).
//
// R3 == R2 resubmit (R2 bench was an infra failure: "container failed twice",
// no kernel-level signal; code audit found no fault mechanism).
// R2 changes vs R1 (869 us):
//  * Q/K/V GEMMs merged into ONE 1536-block dispatch (R1 ran 3x 512-block
//    dispatches = 2 blocks/CU grid-limited, with full drains between). sec =
//    blockIdx-derived; bijective XCD swizzle gives each XCD 8 contiguous
//    m-panels (A reuse in its private L2).
//  * V^T written directly from the V-section epilogue as vectorized ushort4
//    stores (consecutive regs = consecutive s-rows) -> vtrans kernel deleted.
//  * attn: K/V per bh is 128 KB and L2-resident (8 q-blocks reuse it) ->
//    MFMA fragments are loaded DIRECTLY from global (per-lane b128, 64B
//    segments) instead of LDS staging. LDS keeps only the wave-private P
//    buffer (18.4 KB). The chunk loop is now ZERO-barrier; waves are fully
//    independent; __launch_bounds__(256,4) -> 16 waves/CU.

typedef __bf16 bf16x8 __attribute__((ext_vector_type(8)));
typedef float  f32x4  __attribute__((ext_vector_type(4)));

#define MFMA(a, b, c) __builtin_amdgcn_mfma_f32_16x16x32_bf16(a, b, c, 0, 0, 0)
#define NEG_BIG (-1e30f)
#define PL ((size_t)8388608)      // elems per projection plane (16*16*512*64)
#define WN ((size_t)1048576)      // elems per W plane (1024*1024)

static __device__ __forceinline__ unsigned pk_hi(float a, float b) {
    return (__float_as_uint(a) >> 16) | (__float_as_uint(b) & 0xFFFF0000u);
}
static __device__ __forceinline__ float trf(float x) {
    return __uint_as_float(__float_as_uint(x) & 0xFFFF0000u);
}
static __device__ __forceinline__ unsigned rne16(float x) {
    unsigned b = __float_as_uint(x);
    return (b + 0x7FFFu + ((b >> 16) & 1u)) >> 16;
}
static __device__ __forceinline__ ushort hi16(float x) {
    return (ushort)(__float_as_uint(x) >> 16);
}
// Swizzled LDS fragment read: tile stored as [row][8 groups of 8 bf16],
// group XOR-swizzled by (row&7) so ds_read_b128 is bank-uniform.
static __device__ __forceinline__ bf16x8 ldfrag(const ushort* base, int row, int grp) {
    return *(const bf16x8*)(base + (((row << 3) + (grp ^ (row & 7))) << 3));
}
static __device__ __forceinline__ void gl_lds16(const ushort* g, ushort* l) {
    __builtin_amdgcn_global_load_lds(
        (const __attribute__((address_space(1))) void*)g,
        (__attribute__((address_space(3))) void*)l, 16, 0, 0);
}

// ---------------------------------------------------------------------------
// K0: fp32 -> (hi trunc bf16, lo rne residual bf16) planes. 8 elems/thread.
// ---------------------------------------------------------------------------
__global__ __launch_bounds__(256) void split_planes(
    const float* __restrict__ in, ushort* __restrict__ oh,
    ushort* __restrict__ ol, int n8)
{
    for (int i = blockIdx.x * 256 + threadIdx.x; i < n8; i += gridDim.x * 256) {
        float4 f0 = ((const float4*)in)[2 * i], f1 = ((const float4*)in)[2 * i + 1];
        uint4 hv, lv;
        hv.x = pk_hi(f0.x, f0.y); hv.y = pk_hi(f0.z, f0.w);
        hv.z = pk_hi(f1.x, f1.y); hv.w = pk_hi(f1.z, f1.w);
        lv.x = rne16(f0.x - trf(f0.x)) | (rne16(f0.y - trf(f0.y)) << 16);
        lv.y = rne16(f0.z - trf(f0.z)) | (rne16(f0.w - trf(f0.w)) << 16);
        lv.z = rne16(f1.x - trf(f1.x)) | (rne16(f1.y - trf(f1.y)) << 16);
        lv.w = rne16(f1.z - trf(f1.z)) | (rne16(f1.w - trf(f1.w)) << 16);
        ((uint4*)oh)[i] = hv;
        ((uint4*)ol)[i] = lv;
    }
}

// ---------------------------------------------------------------------------
// K1: merged QKV projection. grid = (24, 64): sec = bx>>3 (0=Q,1=K,2=V).
// 128x128 tile, BK=32, 4 waves, per-wave 64x64 via 4x4 grid of 16x16x32 MFMA.
// LDS row: 8 groups of 16B = [hi k-grp 0..3 | lo k-grp 0..3], XOR(r&7).
// Staging via global_load_lds (linear dest, pre-swizzled per-lane source).
// sec 0/1 epilogue -> [bh][s][dd] hi/lo planes; sec 2 -> transposed
// [bh][dd][s] planes via ushort4 stores (vtrans folded in).
// ---------------------------------------------------------------------------
__global__ __launch_bounds__(256, 3) void qkv3_mfma(
    const ushort* __restrict__ xh, const ushort* __restrict__ xl,
    const ushort* __restrict__ wall,
    const float* __restrict__ bq, const float* __restrict__ bk,
    const float* __restrict__ bv,
    ushort* __restrict__ qkout, ushort* __restrict__ vth, ushort* __restrict__ vtl)
{
    __shared__ __align__(16) ushort As[8192], Bs[8192];
    // bijective XCD swizzle over 1536 blocks (1536 % 8 == 0): each XCD gets
    // 192 contiguous logical blocks = 8 m-panel rows -> A reuse in its L2.
    const int lin = blockIdx.y * 24 + blockIdx.x;
    const int nl = (lin & 7) * 192 + (lin >> 3);
    const int bx = nl % 24, by = nl / 24;
    const int sec = bx >> 3, nx = bx & 7;
    const int n0 = nx * 128, m0 = by * 128;
    const ushort* wh = wall + (size_t)sec * 2 * WN;
    const ushort* wl = wh + WN;
    const float* bias = (sec == 0) ? bq : (sec == 1) ? bk : bv;

    const int t = threadIdx.x, w = t >> 6, lane = t & 63;
    const int quad = lane >> 4, l15 = lane & 15;
    const int wr = w >> 1, wc = w & 1;

    const f32x4 zero = {0.f, 0.f, 0.f, 0.f};
    f32x4 acc[4][4];
#pragma unroll
    for (int i = 0; i < 4; ++i)
#pragma unroll
        for (int j = 0; j < 4; ++j) acc[i][j] = zero;

    for (int kc = 0; kc < 1024; kc += 32) {
        __syncthreads();
#pragma unroll
        for (int rep = 0; rep < 8; ++rep) {
            int slot = t + (rep & 3) * 256;         // 1024 slots: 128 rows x 8 grp
            int r = slot >> 3, gs = slot & 7;
            int g = gs ^ (r & 7);                   // logical group this slot holds
            int kg = g & 3;                         // k-subgroup (8 bf16)
            if (rep < 4) {
                const ushort* base = (g & 4) ? xl : xh;
                gl_lds16(base + (size_t)(m0 + r) * 1024 + kc + kg * 8,
                         &As[((rep & 3) * 256 + w * 64) * 8]);
            } else {
                const ushort* base = (g & 4) ? wl : wh;
                gl_lds16(base + (size_t)(n0 + r) * 1024 + kc + kg * 8,
                         &Bs[((rep & 3) * 256 + w * 64) * 8]);
            }
        }
        __syncthreads();
        bf16x8 ah[4], al4[4], bh4[4], bl4[4];
#pragma unroll
        for (int i = 0; i < 4; ++i) {
            int row = wr * 64 + i * 16 + l15;
            ah[i]  = ldfrag(As, row, quad);         // hi: groups 0..3
            al4[i] = ldfrag(As, row, 4 + quad);     // lo: groups 4..7
        }
#pragma unroll
        for (int j = 0; j < 4; ++j) {
            int row = wc * 64 + j * 16 + l15;
            bh4[j] = ldfrag(Bs, row, quad);
            bl4[j] = ldfrag(Bs, row, 4 + quad);
        }
#pragma unroll
        for (int i = 0; i < 4; ++i)
#pragma unroll
            for (int j = 0; j < 4; ++j) {
                acc[i][j] = MFMA(ah[i],  bh4[j], acc[i][j]);
                acc[i][j] = MFMA(ah[i],  bl4[j], acc[i][j]);
                acc[i][j] = MFMA(al4[i], bh4[j], acc[i][j]);
            }
    }

    if (sec < 2) {
        ushort* oh = qkout + (size_t)sec * 2 * PL;
        ushort* ol = oh + PL;
#pragma unroll
        for (int j = 0; j < 4; ++j) {
            int n = n0 + wc * 64 + j * 16 + l15;
            float bb = bias[n];
            int h = n >> 6, dd = n & 63;
#pragma unroll
            for (int i = 0; i < 4; ++i)
#pragma unroll
                for (int reg = 0; reg < 4; ++reg) {
                    int m = m0 + wr * 64 + i * 16 + quad * 4 + reg;
                    int b = m >> 9, s = m & 511;
                    float c = acc[i][j][reg] + bb;
                    size_t o = (((size_t)(b * 16 + h)) * 512 + s) * 64 + dd;
                    oh[o] = hi16(c);
                    ol[o] = (ushort)rne16(c - trf(c));
                }
        }
    } else {
        // V: write transposed planes [bh][dd][s]; 4 consecutive regs = 4
        // consecutive s -> ushort4 stores (8B aligned: s0 % 4 == 0).
#pragma unroll
        for (int j = 0; j < 4; ++j) {
            int n = n0 + wc * 64 + j * 16 + l15;
            float bb = bias[n];
            int h = n >> 6, dd = n & 63;
#pragma unroll
            for (int i = 0; i < 4; ++i) {
                int m = m0 + wr * 64 + i * 16 + quad * 4;
                int b = m >> 9, s = m & 511;
                float c0 = acc[i][j][0] + bb, c1 = acc[i][j][1] + bb;
                float c2 = acc[i][j][2] + bb, c3 = acc[i][j][3] + bb;
                ushort4 hv, lv;
                hv.x = hi16(c0); hv.y = hi16(c1); hv.z = hi16(c2); hv.w = hi16(c3);
                lv.x = (ushort)rne16(c0 - trf(c0));
                lv.y = (ushort)rne16(c1 - trf(c1));
                lv.z = (ushort)rne16(c2 - trf(c2));
                lv.w = (ushort)rne16(c3 - trf(c3));
                size_t o = (((size_t)(b * 16 + h)) * 64 + dd) * 512 + s;
                *(ushort4*)&vth[o] = hv;
                *(ushort4*)&vtl[o] = lv;
            }
        }
    }
}

// ---------------------------------------------------------------------------
// K2: fused attention, ZERO-barrier chunk loop. Per (64-q-row tile, bh):
// QK^T (3-MFMA, K frags direct from global) -> scale/mask -> sc write ->
// online softmax -> P*gp -> wave-private LDS (C->A layout) -> PV (3-MFMA,
// V^T frags direct from global) -> ctx. Each of 4 waves owns 16 q-rows;
// waves are fully independent (K/V is L2-resident; no LDS staging).
// ---------------------------------------------------------------------------
__global__ __launch_bounds__(256, 4) void attn_fused(
    const ushort* __restrict__ qh, const ushort* __restrict__ ql,
    const ushort* __restrict__ kh, const ushort* __restrict__ kl,
    const ushort* __restrict__ vth, const ushort* __restrict__ vtl,
    const int* __restrict__ mask, const float* __restrict__ gp,
    float* __restrict__ sc, float* __restrict__ ctx)
{
    __shared__ __align__(16) ushort P[9216];       // per wave: hi[1152] lo[1152]

    const int bh = blockIdx.y, b = bh >> 4, h = bh & 15;
    const int q0 = blockIdx.x * 64;
    const int t = threadIdx.x, w = t >> 6, lane = t & 63;
    const int quad = lane >> 4, l15 = lane & 15;

    ushort* phb = P + w * 2304;
    ushort* plb = phb + 1152;

    // Q fragments direct from global (one-time)
    bf16x8 qfh[2], qfl[2];
    {
        size_t qoff = ((size_t)bh * 512 + q0 + w * 16 + l15) * 64 + quad * 8;
#pragma unroll
        for (int ks = 0; ks < 2; ++ks) {
            qfh[ks] = *(const bf16x8*)(qh + qoff + ks * 32);
            qfl[ks] = *(const bf16x8*)(ql + qoff + ks * 32);
        }
    }

    float m_run[4] = {-INFINITY, -INFINITY, -INFINITY, -INFINITY};
    float l_run[4] = {0.f, 0.f, 0.f, 0.f};
    const f32x4 zero = {0.f, 0.f, 0.f, 0.f};
    f32x4 accO[4];
#pragma unroll
    for (int d = 0; d < 4; ++d) accO[d] = zero;

    int rowg[4];
#pragma unroll
    for (int reg = 0; reg < 4; ++reg) rowg[reg] = q0 + w * 16 + quad * 4 + reg;

    const size_t kbase = (size_t)bh * 512 * 64;    // K planes [s][dd]
    const size_t vbase = (size_t)bh * 64 * 512;    // V^T planes [dd][s]
    const size_t mrow = (size_t)b * 262144;
    const size_t srow = (size_t)bh * 262144;

    for (int c = 0; c < 8; ++c) {
        // QK^T for this 64-col chunk (K frags direct from global; L1/L2 hit)
        float sv[4][4];                              // [nt][reg]
#pragma unroll
        for (int nt = 0; nt < 4; ++nt) {
            size_t koff = kbase + (size_t)(c * 64 + nt * 16 + l15) * 64 + quad * 8;
            f32x4 a = zero;
#pragma unroll
            for (int ks = 0; ks < 2; ++ks) {
                bf16x8 kfh = *(const bf16x8*)(kh + koff + ks * 32);
                bf16x8 kfl = *(const bf16x8*)(kl + koff + ks * 32);
                a = MFMA(qfh[ks], kfh, a);
                a = MFMA(qfh[ks], kfl, a);
                a = MFMA(qfl[ks], kfh, a);
            }
            int col = c * 64 + nt * 16 + l15;
#pragma unroll
            for (int reg = 0; reg < 4; ++reg) {
                int row = rowg[reg];
                int mv = mask[mrow + (size_t)row * 512 + col];
                float x = a[reg] * 0.125f;
                float val = (mv | (row == col)) ? x : NEG_BIG;
                sc[srow + (size_t)row * 512 + col] = val;
                sv[nt][reg] = val;
            }
        }
        // online softmax update (per reg = per q-row)
        float alpha[4];
#pragma unroll
        for (int reg = 0; reg < 4; ++reg) {
            float cm = fmaxf(fmaxf(sv[0][reg], sv[1][reg]), fmaxf(sv[2][reg], sv[3][reg]));
            cm = fmaxf(cm, __shfl_xor(cm, 1));
            cm = fmaxf(cm, __shfl_xor(cm, 2));
            cm = fmaxf(cm, __shfl_xor(cm, 4));
            cm = fmaxf(cm, __shfl_xor(cm, 8));
            float mn = fmaxf(m_run[reg], cm);
            alpha[reg] = __expf(m_run[reg] - mn);
            m_run[reg] = mn;
            float rs = 0.f;
#pragma unroll
            for (int nt = 0; nt < 4; ++nt) {
                float e = (sv[nt][reg] > -5e29f) ? __expf(sv[nt][reg] - mn) : 0.f;
                sv[nt][reg] = e;                     // reuse as p (no gp)
                rs += e;
            }
            rs += __shfl_xor(rs, 1);
            rs += __shfl_xor(rs, 2);
            rs += __shfl_xor(rs, 4);
            rs += __shfl_xor(rs, 8);
            l_run[reg] = l_run[reg] * alpha[reg] + rs;
        }
        // P = p * gp -> wave-private LDS (hi/lo), C-layout -> A-layout
#pragma unroll
        for (int nt = 0; nt < 4; ++nt) {
            int col = c * 64 + nt * 16 + l15;
#pragma unroll
            for (int reg = 0; reg < 4; ++reg) {
                float g = gp[mrow + (size_t)rowg[reg] * 512 + col];
                float pv = sv[nt][reg] * g;
                int a_ = (quad * 4 + reg) * 72 + nt * 16 + l15;
                phb[a_] = hi16(pv);
                plb[a_] = (ushort)rne16(pv - trf(pv));
            }
        }
        // rescale O by alpha, then accumulate chunk's P@V (V^T direct global)
#pragma unroll
        for (int d = 0; d < 4; ++d)
#pragma unroll
            for (int reg = 0; reg < 4; ++reg) accO[d][reg] *= alpha[reg];
#pragma unroll
        for (int ks = 0; ks < 2; ++ks) {
            bf16x8 pfh = *(const bf16x8*)&phb[l15 * 72 + ks * 32 + quad * 8];
            bf16x8 pfl = *(const bf16x8*)&plb[l15 * 72 + ks * 32 + quad * 8];
#pragma unroll
            for (int d = 0; d < 4; ++d) {
                size_t voff = vbase + (size_t)(d * 16 + l15) * 512
                            + c * 64 + ks * 32 + quad * 8;
                bf16x8 vfh = *(const bf16x8*)(vth + voff);
                bf16x8 vfl = *(const bf16x8*)(vtl + voff);
                accO[d] = MFMA(pfh, vfh, accO[d]);
                accO[d] = MFMA(pfh, vfl, accO[d]);
                accO[d] = MFMA(pfl, vfh, accO[d]);
            }
        }
    }
    // epilogue: ctx = O / l
#pragma unroll
    for (int reg = 0; reg < 4; ++reg) {
        float inv = 1.f / l_run[reg];
#pragma unroll
        for (int d = 0; d < 4; ++d)
            ctx[((size_t)b * 512 + rowg[reg]) * 1024 + h * 64 + d * 16 + l15] =
                accO[d][reg] * inv;
    }
}

// ---------------------------------------------------------------------------
extern "C" void kernel_launch(void* const* d_in, const int* in_sizes, int n_in,
                              void* d_out, int out_size, void* d_ws, size_t ws_size,
                              hipStream_t stream) {
    const float* hs   = (const float*)d_in[0];
    const int*   mask = (const int*)d_in[1];
    const float* gp   = (const float*)d_in[2];
    const float* Wq   = (const float*)d_in[3];
    const float* bq   = (const float*)d_in[4];
    const float* Wk   = (const float*)d_in[5];
    const float* bk   = (const float*)d_in[6];
    const float* Wv   = (const float*)d_in[7];
    const float* bv   = (const float*)d_in[8];

    float* out = (float*)d_out;
    float* ctx = out;                                  // [16,512,1024]
    float* sc  = out + (size_t)16 * 512 * 1024;        // [16,16,512,512]

    // persistent planes in d_ws: [qh ql kh kl][vth vtl], 6 x PL (100.66 MB)
    ushort* qkout = (ushort*)d_ws;
    ushort* qhp   = qkout;
    ushort* qlp   = qhp + PL;
    ushort* khp   = qlp + PL;
    ushort* klp   = khp + PL;
    ushort* vthp  = klp + PL;
    ushort* vtlp  = vthp + PL;

    // pre-attn scratch in the sc output region (dead until attn_fused):
    // [xh xl][6 W planes] = 45.6 MB << 268.4 MB
    ushort* xh   = (ushort*)sc;
    ushort* xl   = xh + PL;
    ushort* wall = xl + PL;                            // wqh wql wkh wkl wvh wvl

    dim3 blk(256);
    split_planes<<<dim3(2048), blk, 0, stream>>>(hs, xh, xl, (int)(PL / 8));
    split_planes<<<dim3(512),  blk, 0, stream>>>(Wq, wall + 0 * WN, wall + 1 * WN, (int)(WN / 8));
    split_planes<<<dim3(512),  blk, 0, stream>>>(Wk, wall + 2 * WN, wall + 3 * WN, (int)(WN / 8));
    split_planes<<<dim3(512),  blk, 0, stream>>>(Wv, wall + 4 * WN, wall + 5 * WN, (int)(WN / 8));
    qkv3_mfma<<<dim3(24, 64), blk, 0, stream>>>(xh, xl, wall, bq, bk, bv,
                                                qkout, vthp, vtlp);
    attn_fused<<<dim3(8, 256), blk, 0, stream>>>(qhp, qlp, khp, klp, vthp, vtlp,
                                                 mask, gp, sc, ctx);
}

// Round 4
// 754.510 us; speedup vs baseline: 1.2926x; 1.2926x over previous
//
#include <hip/hip_runtime.h>
#include <cmath>

// Problem: B=16, S=512, H=1024, NH=16, DH=64.
// out = [ctx 16x512x1024][scores 16x16x512x512], fp32.
// Strategy: split-fp32 (hi/lo bf16, 3-term MFMA) for all GEMM-shaped work.
//   x = hi(trunc) + lo(rne residual); A*B ~= Ah*Bh + Ah*Bl + Al*Bh (err ~2^-17).
// Masked scores written as -1e30 (finite; exp(-1e30 - m) == 0 so softmax ok).
//
// R4 changes vs R3 (975 us; attn 500, qkv phase ~475):
//  * attn: R3's direct-global K/V frags re-fetched from HBM (FETCH 295->530MB,
//    L2 thrash across bh planes) -> restore LDS staging, but K and V^T now
//    TIME-SHARE one 16 KB buffer pair (4-barrier chunk loop; V's gl_lds issue
//    overlaps the whole mask/sc/softmax/gp phase). LDS 51.2 -> 34.8 KB ->
//    4 blocks/CU.
//  * qkv3: XCD partition flipped from m-panel-major (each XCD streamed all
//    12 MB of W per panel round -> ~768 MB latency-exposed W fetch) to
//    COLUMN-major: each XCD owns 3 W-column-tiles (1.5 MB, L2-resident) and
//    all 64 X panels; the 3 column-blocks per panel are dispatch-adjacent so
//    they co-fetch X (X streamed once per XCD).

typedef __bf16 bf16x8 __attribute__((ext_vector_type(8)));
typedef float  f32x4  __attribute__((ext_vector_type(4)));

#define MFMA(a, b, c) __builtin_amdgcn_mfma_f32_16x16x32_bf16(a, b, c, 0, 0, 0)
#define NEG_BIG (-1e30f)
#define PL ((size_t)8388608)      // elems per projection plane (16*16*512*64)
#define WN ((size_t)1048576)      // elems per W plane (1024*1024)

static __device__ __forceinline__ unsigned pk_hi(float a, float b) {
    return (__float_as_uint(a) >> 16) | (__float_as_uint(b) & 0xFFFF0000u);
}
static __device__ __forceinline__ float trf(float x) {
    return __uint_as_float(__float_as_uint(x) & 0xFFFF0000u);
}
static __device__ __forceinline__ unsigned rne16(float x) {
    unsigned b = __float_as_uint(x);
    return (b + 0x7FFFu + ((b >> 16) & 1u)) >> 16;
}
static __device__ __forceinline__ ushort hi16(float x) {
    return (ushort)(__float_as_uint(x) >> 16);
}
// Swizzled LDS fragment read: tile stored as [row][8 groups of 8 bf16],
// group XOR-swizzled by (row&7) so ds_read_b128 is bank-uniform.
static __device__ __forceinline__ bf16x8 ldfrag(const ushort* base, int row, int grp) {
    return *(const bf16x8*)(base + (((row << 3) + (grp ^ (row & 7))) << 3));
}
static __device__ __forceinline__ void gl_lds16(const ushort* g, ushort* l) {
    __builtin_amdgcn_global_load_lds(
        (const __attribute__((address_space(1))) void*)g,
        (__attribute__((address_space(3))) void*)l, 16, 0, 0);
}

// ---------------------------------------------------------------------------
// K0: fp32 -> (hi trunc bf16, lo rne residual bf16) planes. 8 elems/thread.
// ---------------------------------------------------------------------------
__global__ __launch_bounds__(256) void split_planes(
    const float* __restrict__ in, ushort* __restrict__ oh,
    ushort* __restrict__ ol, int n8)
{
    for (int i = blockIdx.x * 256 + threadIdx.x; i < n8; i += gridDim.x * 256) {
        float4 f0 = ((const float4*)in)[2 * i], f1 = ((const float4*)in)[2 * i + 1];
        uint4 hv, lv;
        hv.x = pk_hi(f0.x, f0.y); hv.y = pk_hi(f0.z, f0.w);
        hv.z = pk_hi(f1.x, f1.y); hv.w = pk_hi(f1.z, f1.w);
        lv.x = rne16(f0.x - trf(f0.x)) | (rne16(f0.y - trf(f0.y)) << 16);
        lv.y = rne16(f0.z - trf(f0.z)) | (rne16(f0.w - trf(f0.w)) << 16);
        lv.z = rne16(f1.x - trf(f1.x)) | (rne16(f1.y - trf(f1.y)) << 16);
        lv.w = rne16(f1.z - trf(f1.z)) | (rne16(f1.w - trf(f1.w)) << 16);
        ((uint4*)oh)[i] = hv;
        ((uint4*)ol)[i] = lv;
    }
}

// ---------------------------------------------------------------------------
// K1: merged QKV projection. grid = (24, 64) = 1536 blocks.
// XCD partition (HW round-robin lin%8): xcd owns columns c = xcd*3..xcd*3+2
// (W slice 1.5 MB -> L2-resident) and all 64 X panels; by = (lin>>3)/3 so the
// 3 column-blocks of a panel are dispatch-adjacent (co-fetch X).
// 128x128 tile, BK=32, 4 waves, per-wave 64x64 via 4x4 grid of 16x16x32 MFMA.
// LDS row: 8 groups of 16B = [hi k-grp 0..3 | lo k-grp 0..3], XOR(r&7).
// sec 0/1 epilogue -> [bh][s][dd] hi/lo planes; sec 2 -> transposed
// [bh][dd][s] planes via ushort4 stores.
// ---------------------------------------------------------------------------
__global__ __launch_bounds__(256, 3) void qkv3_mfma(
    const ushort* __restrict__ xh, const ushort* __restrict__ xl,
    const ushort* __restrict__ wall,
    const float* __restrict__ bq, const float* __restrict__ bk,
    const float* __restrict__ bv,
    ushort* __restrict__ qkout, ushort* __restrict__ vth, ushort* __restrict__ vtl)
{
    __shared__ __align__(16) ushort As[8192], Bs[8192];
    const int lin = blockIdx.y * 24 + blockIdx.x;
    const int xcd = lin & 7, local = lin >> 3;      // local in [0,192)
    const int by = local / 3;                       // X panel 0..63
    const int c  = xcd * 3 + (local - 3 * by);      // column 0..23
    const int sec = c >> 3, nx = c & 7;
    const int n0 = nx * 128, m0 = by * 128;
    const ushort* wh = wall + (size_t)sec * 2 * WN;
    const ushort* wl = wh + WN;
    const float* bias = (sec == 0) ? bq : (sec == 1) ? bk : bv;

    const int t = threadIdx.x, w = t >> 6, lane = t & 63;
    const int quad = lane >> 4, l15 = lane & 15;
    const int wr = w >> 1, wc = w & 1;

    const f32x4 zero = {0.f, 0.f, 0.f, 0.f};
    f32x4 acc[4][4];
#pragma unroll
    for (int i = 0; i < 4; ++i)
#pragma unroll
        for (int j = 0; j < 4; ++j) acc[i][j] = zero;

    for (int kc = 0; kc < 1024; kc += 32) {
        __syncthreads();
#pragma unroll
        for (int rep = 0; rep < 8; ++rep) {
            int slot = t + (rep & 3) * 256;         // 1024 slots: 128 rows x 8 grp
            int r = slot >> 3, gs = slot & 7;
            int g = gs ^ (r & 7);                   // logical group this slot holds
            int kg = g & 3;                         // k-subgroup (8 bf16)
            if (rep < 4) {
                const ushort* base = (g & 4) ? xl : xh;
                gl_lds16(base + (size_t)(m0 + r) * 1024 + kc + kg * 8,
                         &As[((rep & 3) * 256 + w * 64) * 8]);
            } else {
                const ushort* base = (g & 4) ? wl : wh;
                gl_lds16(base + (size_t)(n0 + r) * 1024 + kc + kg * 8,
                         &Bs[((rep & 3) * 256 + w * 64) * 8]);
            }
        }
        __syncthreads();
        bf16x8 ah[4], al4[4], bh4[4], bl4[4];
#pragma unroll
        for (int i = 0; i < 4; ++i) {
            int row = wr * 64 + i * 16 + l15;
            ah[i]  = ldfrag(As, row, quad);         // hi: groups 0..3
            al4[i] = ldfrag(As, row, 4 + quad);     // lo: groups 4..7
        }
#pragma unroll
        for (int j = 0; j < 4; ++j) {
            int row = wc * 64 + j * 16 + l15;
            bh4[j] = ldfrag(Bs, row, quad);
            bl4[j] = ldfrag(Bs, row, 4 + quad);
        }
#pragma unroll
        for (int i = 0; i < 4; ++i)
#pragma unroll
            for (int j = 0; j < 4; ++j) {
                acc[i][j] = MFMA(ah[i],  bh4[j], acc[i][j]);
                acc[i][j] = MFMA(ah[i],  bl4[j], acc[i][j]);
                acc[i][j] = MFMA(al4[i], bh4[j], acc[i][j]);
            }
    }

    if (sec < 2) {
        ushort* oh = qkout + (size_t)sec * 2 * PL;
        ushort* ol = oh + PL;
#pragma unroll
        for (int j = 0; j < 4; ++j) {
            int n = n0 + wc * 64 + j * 16 + l15;
            float bb = bias[n];
            int h = n >> 6, dd = n & 63;
#pragma unroll
            for (int i = 0; i < 4; ++i)
#pragma unroll
                for (int reg = 0; reg < 4; ++reg) {
                    int m = m0 + wr * 64 + i * 16 + quad * 4 + reg;
                    int b = m >> 9, s = m & 511;
                    float cc = acc[i][j][reg] + bb;
                    size_t o = (((size_t)(b * 16 + h)) * 512 + s) * 64 + dd;
                    oh[o] = hi16(cc);
                    ol[o] = (ushort)rne16(cc - trf(cc));
                }
        }
    } else {
        // V: write transposed planes [bh][dd][s]; 4 consecutive regs = 4
        // consecutive s -> ushort4 stores (8B aligned: s0 % 4 == 0).
#pragma unroll
        for (int j = 0; j < 4; ++j) {
            int n = n0 + wc * 64 + j * 16 + l15;
            float bb = bias[n];
            int h = n >> 6, dd = n & 63;
#pragma unroll
            for (int i = 0; i < 4; ++i) {
                int m = m0 + wr * 64 + i * 16 + quad * 4;
                int b = m >> 9, s = m & 511;
                float c0 = acc[i][j][0] + bb, c1 = acc[i][j][1] + bb;
                float c2 = acc[i][j][2] + bb, c3 = acc[i][j][3] + bb;
                ushort4 hv, lv;
                hv.x = hi16(c0); hv.y = hi16(c1); hv.z = hi16(c2); hv.w = hi16(c3);
                lv.x = (ushort)rne16(c0 - trf(c0));
                lv.y = (ushort)rne16(c1 - trf(c1));
                lv.z = (ushort)rne16(c2 - trf(c2));
                lv.w = (ushort)rne16(c3 - trf(c3));
                size_t o = (((size_t)(b * 16 + h)) * 64 + dd) * 512 + s;
                *(ushort4*)&vth[o] = hv;
                *(ushort4*)&vtl[o] = lv;
            }
        }
    }
}

// ---------------------------------------------------------------------------
// K2: fused attention. Per (64-q-row tile, bh), per 64-col chunk:
//   A: barrier (S free)  -> stage K chunk (gl_lds, swizzled source)
//   B: barrier (K ready) -> QK^T (3-MFMA from LDS)
//   C: barrier (K reads done) -> issue V^T gl_lds into SAME buffers, then
//      mask/scale/sc-write/online-softmax/gp/P-LDS-writes (overlaps V load)
//   D: barrier (V+P ready) -> PV (3-MFMA)
// K and V^T time-share one 16 KB buffer pair; P is wave-private (18 KB).
// LDS 34.8 KB -> 4 blocks/CU.
// ---------------------------------------------------------------------------
__global__ __launch_bounds__(256, 4) void attn_fused(
    const ushort* __restrict__ qh, const ushort* __restrict__ ql,
    const ushort* __restrict__ kh, const ushort* __restrict__ kl,
    const ushort* __restrict__ vth, const ushort* __restrict__ vtl,
    const int* __restrict__ mask, const float* __restrict__ gp,
    float* __restrict__ sc, float* __restrict__ ctx)
{
    __shared__ __align__(16) ushort Sh[4096], Sl[4096];  // K chunk, then V^T chunk
    __shared__ __align__(16) ushort P[9216];             // per wave: hi[1152] lo[1152]

    const int bh = blockIdx.y, b = bh >> 4, h = bh & 15;
    const int q0 = blockIdx.x * 64;
    const int t = threadIdx.x, w = t >> 6, lane = t & 63;
    const int quad = lane >> 4, l15 = lane & 15;

    ushort* phb = P + w * 2304;
    ushort* plb = phb + 1152;

    // stage Q tile through the S buffers (one-time)
#pragma unroll
    for (int rep = 0; rep < 2; ++rep) {
        int slot = t + rep * 256;                   // 512 slots: 64 rows x 8 grp
        int r = slot >> 3, gs = slot & 7, g = gs ^ (r & 7);
        size_t src = ((size_t)bh * 512 + q0 + r) * 64 + g * 8;
        int db = (rep * 256 + w * 64) * 8;
        gl_lds16(&qh[src], &Sh[db]);
        gl_lds16(&ql[src], &Sl[db]);
    }
    __syncthreads();
    bf16x8 qfh[2], qfl[2];
    {
        int qrow = w * 16 + l15;
#pragma unroll
        for (int ks = 0; ks < 2; ++ks) {
            qfh[ks] = ldfrag(Sh, qrow, ks * 4 + quad);
            qfl[ks] = ldfrag(Sl, qrow, ks * 4 + quad);
        }
    }

    float m_run[4] = {-INFINITY, -INFINITY, -INFINITY, -INFINITY};
    float l_run[4] = {0.f, 0.f, 0.f, 0.f};
    const f32x4 zero = {0.f, 0.f, 0.f, 0.f};
    f32x4 accO[4];
#pragma unroll
    for (int d = 0; d < 4; ++d) accO[d] = zero;

    int rowg[4];
#pragma unroll
    for (int reg = 0; reg < 4; ++reg) rowg[reg] = q0 + w * 16 + quad * 4 + reg;

    const size_t mrow = (size_t)b * 262144;
    const size_t srow = (size_t)bh * 262144;

    for (int c = 0; c < 8; ++c) {
        __syncthreads();   // A: S buffers free (Q frags read / prev PV done)
        // stage K chunk (swizzled source, linear dest)
#pragma unroll
        for (int rep = 0; rep < 2; ++rep) {
            int slot = t + rep * 256;
            int r = slot >> 3, gs = slot & 7, g = gs ^ (r & 7);
            size_t src = ((size_t)bh * 512 + c * 64 + r) * 64 + g * 8;
            int db = (rep * 256 + w * 64) * 8;
            gl_lds16(&kh[src], &Sh[db]);
            gl_lds16(&kl[src], &Sl[db]);
        }
        __syncthreads();   // B: K ready

        // QK^T for this 64-col chunk
        f32x4 a4[4];
#pragma unroll
        for (int nt = 0; nt < 4; ++nt) {
            f32x4 a = zero;
#pragma unroll
            for (int ks = 0; ks < 2; ++ks) {
                int krow = nt * 16 + l15;
                bf16x8 kfh = ldfrag(Sh, krow, ks * 4 + quad);
                bf16x8 kfl = ldfrag(Sl, krow, ks * 4 + quad);
                a = MFMA(qfh[ks], kfh, a);
                a = MFMA(qfh[ks], kfl, a);
                a = MFMA(qfl[ks], kfh, a);
            }
            a4[nt] = a;
        }
        __syncthreads();   // C: K LDS reads done -> S reusable for V
        // issue V^T staging now; its latency hides under the softmax phase
#pragma unroll
        for (int rep = 0; rep < 2; ++rep) {
            int slot = t + rep * 256;
            int r = slot >> 3, gs = slot & 7, g = gs ^ (r & 7);  // r=dd, g=s-grp
            size_t src = ((size_t)bh * 64 + r) * 512 + c * 64 + g * 8;
            int db = (rep * 256 + w * 64) * 8;
            gl_lds16(&vth[src], &Sh[db]);
            gl_lds16(&vtl[src], &Sl[db]);
        }

        // mask/scale -> sc write
        float sv[4][4];                              // [nt][reg]
#pragma unroll
        for (int nt = 0; nt < 4; ++nt) {
            int col = c * 64 + nt * 16 + l15;
#pragma unroll
            for (int reg = 0; reg < 4; ++reg) {
                int row = rowg[reg];
                int mv = mask[mrow + (size_t)row * 512 + col];
                float x = a4[nt][reg] * 0.125f;
                float val = (mv | (row == col)) ? x : NEG_BIG;
                sc[srow + (size_t)row * 512 + col] = val;
                sv[nt][reg] = val;
            }
        }
        // online softmax update (per reg = per q-row)
        float alpha[4];
#pragma unroll
        for (int reg = 0; reg < 4; ++reg) {
            float cm = fmaxf(fmaxf(sv[0][reg], sv[1][reg]), fmaxf(sv[2][reg], sv[3][reg]));
            cm = fmaxf(cm, __shfl_xor(cm, 1));
            cm = fmaxf(cm, __shfl_xor(cm, 2));
            cm = fmaxf(cm, __shfl_xor(cm, 4));
            cm = fmaxf(cm, __shfl_xor(cm, 8));
            float mn = fmaxf(m_run[reg], cm);
            alpha[reg] = __expf(m_run[reg] - mn);
            m_run[reg] = mn;
            float rs = 0.f;
#pragma unroll
            for (int nt = 0; nt < 4; ++nt) {
                float e = (sv[nt][reg] > -5e29f) ? __expf(sv[nt][reg] - mn) : 0.f;
                sv[nt][reg] = e;                     // reuse as p (no gp)
                rs += e;
            }
            rs += __shfl_xor(rs, 1);
            rs += __shfl_xor(rs, 2);
            rs += __shfl_xor(rs, 4);
            rs += __shfl_xor(rs, 8);
            l_run[reg] = l_run[reg] * alpha[reg] + rs;
        }
        // P = p * gp -> wave-private LDS (hi/lo), C-layout -> A-layout
#pragma unroll
        for (int nt = 0; nt < 4; ++nt) {
            int col = c * 64 + nt * 16 + l15;
#pragma unroll
            for (int reg = 0; reg < 4; ++reg) {
                float g = gp[mrow + (size_t)rowg[reg] * 512 + col];
                float pv = sv[nt][reg] * g;
                int a_ = (quad * 4 + reg) * 72 + nt * 16 + l15;
                phb[a_] = hi16(pv);
                plb[a_] = (ushort)rne16(pv - trf(pv));
            }
        }
        // rescale O by alpha
#pragma unroll
        for (int d = 0; d < 4; ++d)
#pragma unroll
            for (int reg = 0; reg < 4; ++reg) accO[d][reg] *= alpha[reg];
        __syncthreads();   // D: V ready, P ready
        // PV accumulate
#pragma unroll
        for (int ks = 0; ks < 2; ++ks) {
            bf16x8 pfh = *(const bf16x8*)&phb[l15 * 72 + ks * 32 + quad * 8];
            bf16x8 pfl = *(const bf16x8*)&plb[l15 * 72 + ks * 32 + quad * 8];
#pragma unroll
            for (int d = 0; d < 4; ++d) {
                bf16x8 vfh = ldfrag(Sh, d * 16 + l15, ks * 4 + quad);
                bf16x8 vfl = ldfrag(Sl, d * 16 + l15, ks * 4 + quad);
                accO[d] = MFMA(pfh, vfh, accO[d]);
                accO[d] = MFMA(pfh, vfl, accO[d]);
                accO[d] = MFMA(pfl, vfh, accO[d]);
            }
        }
    }
    // epilogue: ctx = O / l
#pragma unroll
    for (int reg = 0; reg < 4; ++reg) {
        float inv = 1.f / l_run[reg];
#pragma unroll
        for (int d = 0; d < 4; ++d)
            ctx[((size_t)b * 512 + rowg[reg]) * 1024 + h * 64 + d * 16 + l15] =
                accO[d][reg] * inv;
    }
}

// ---------------------------------------------------------------------------
extern "C" void kernel_launch(void* const* d_in, const int* in_sizes, int n_in,
                              void* d_out, int out_size, void* d_ws, size_t ws_size,
                              hipStream_t stream) {
    const float* hs   = (const float*)d_in[0];
    const int*   mask = (const int*)d_in[1];
    const float* gp   = (const float*)d_in[2];
    const float* Wq   = (const float*)d_in[3];
    const float* bq   = (const float*)d_in[4];
    const float* Wk   = (const float*)d_in[5];
    const float* bk   = (const float*)d_in[6];
    const float* Wv   = (const float*)d_in[7];
    const float* bv   = (const float*)d_in[8];

    float* out = (float*)d_out;
    float* ctx = out;                                  // [16,512,1024]
    float* sc  = out + (size_t)16 * 512 * 1024;        // [16,16,512,512]

    // persistent planes in d_ws: [qh ql kh kl][vth vtl], 6 x PL (100.66 MB)
    ushort* qkout = (ushort*)d_ws;
    ushort* qhp   = qkout;
    ushort* qlp   = qhp + PL;
    ushort* khp   = qlp + PL;
    ushort* klp   = khp + PL;
    ushort* vthp  = klp + PL;
    ushort* vtlp  = vthp + PL;

    // pre-attn scratch in the sc output region (dead until attn_fused):
    // [xh xl][6 W planes] = 45.6 MB << 268.4 MB
    ushort* xh   = (ushort*)sc;
    ushort* xl   = xh + PL;
    ushort* wall = xl + PL;                            // wqh wql wkh wkl wvh wvl

    dim3 blk(256);
    split_planes<<<dim3(2048), blk, 0, stream>>>(hs, xh, xl, (int)(PL / 8));
    split_planes<<<dim3(512),  blk, 0, stream>>>(Wq, wall + 0 * WN, wall + 1 * WN, (int)(WN / 8));
    split_planes<<<dim3(512),  blk, 0, stream>>>(Wk, wall + 2 * WN, wall + 3 * WN, (int)(WN / 8));
    split_planes<<<dim3(512),  blk, 0, stream>>>(Wv, wall + 4 * WN, wall + 5 * WN, (int)(WN / 8));
    qkv3_mfma<<<dim3(24, 64), blk, 0, stream>>>(xh, xl, wall, bq, bk, bv,
                                                qkout, vthp, vtlp);
    attn_fused<<<dim3(8, 256), blk, 0, stream>>>(qhp, qlp, khp, klp, vthp, vtlp,
                                                 mask, gp, sc, ctx);
}